// Round 6
// baseline (216.699 us; speedup 1.0000x reference)
//
#include <hip/hip_runtime.h>
#include <hip/hip_bf16.h>
#include <stdint.h>

#define MROWS 16384   // B*S
#define KDIM  2048
#define NDIM  2048
#define LEAFD 13
#define RANKD 4

typedef __bf16 bf16x8 __attribute__((ext_vector_type(8)));
typedef float  f32x4  __attribute__((ext_vector_type(4)));
typedef float  f32x16 __attribute__((ext_vector_type(16)));

// ---------------------------------------------------------------------------
// Kernel 1: w_bf[o,i] = bf16( weight[o,i] + sum_r L0[r,o2,i2]*L1[r,o1,i1]*L2[r,o0,i0] )
// ---------------------------------------------------------------------------
__global__ void build_w_kernel(const float* __restrict__ weight,
                               const float* __restrict__ leaf,
                               __hip_bfloat16* __restrict__ wbf) {
    __shared__ float ll[3 * RANKD * LEAFD * LEAFD];
    for (int t = threadIdx.x; t < 3 * RANKD * LEAFD * LEAFD; t += blockDim.x)
        ll[t] = leaf[t];
    __syncthreads();
    int idx = blockIdx.x * blockDim.x + threadIdx.x;
    if (idx >= NDIM * KDIM) return;
    int o = idx / KDIM, i = idx % KDIM;
    int o2 = o / 169, o1 = (o / 13) % 13, o0 = o % 13;
    int i2 = i / 169, i1 = (i / 13) % 13, i0 = i % 13;
    float d = 0.f;
#pragma unroll
    for (int r = 0; r < RANKD; ++r) {
        float a = ll[( r            * LEAFD + o2) * LEAFD + i2];
        float b = ll[((RANKD   + r) * LEAFD + o1) * LEAFD + i1];
        float c = ll[((2*RANKD + r) * LEAFD + o0) * LEAFD + i0];
        d += a * b * c;
    }
    wbf[idx] = __float2bfloat16(weight[idx] + d);
}

// ---------------------------------------------------------------------------
// Kernel 2: fp32 -> bf16 conversion of activations (8 floats/thread)
// ---------------------------------------------------------------------------
__global__ void cvt_kernel(const float* __restrict__ x,
                           __hip_bfloat16* __restrict__ xb, int n) {
    long stride = (long)gridDim.x * blockDim.x * 8;
    for (long idx = ((long)blockIdx.x * blockDim.x + threadIdx.x) * 8; idx < n; idx += stride) {
        float4 v0 = *reinterpret_cast<const float4*>(x + idx);
        float4 v1 = *reinterpret_cast<const float4*>(x + idx + 4);
        __hip_bfloat16 tmp[8];
        tmp[0] = __float2bfloat16(v0.x); tmp[1] = __float2bfloat16(v0.y);
        tmp[2] = __float2bfloat16(v0.z); tmp[3] = __float2bfloat16(v0.w);
        tmp[4] = __float2bfloat16(v1.x); tmp[5] = __float2bfloat16(v1.y);
        tmp[6] = __float2bfloat16(v1.z); tmp[7] = __float2bfloat16(v1.w);
        *reinterpret_cast<uint4*>(xb + idx) = *reinterpret_cast<const uint4*>(tmp);
    }
}

// ---------------------------------------------------------------------------
// Kernel 3: 256x256 tile, BK=32, 32x32x16 MFMA, triple-buffered LDS (96 KB).
// 512 threads = 8 waves (2M x 4N); per-wave output 128x64 = 4x2 frags of 32x32.
// LDS RELAYOUT (vs R5): chunk (row r, 16B-slot s) stored at 16B-position
//   p = (r>>5)*128 + (s>>1)*64 + q',  vslot = ((r>>4)&1)|((s&1)<<1),
//   q = (r&15)*4 + vslot,  q' = q ^ ((q>>3)&7).
// Fragment reads then collapse to  base + ks*1024 + qs*16  with
//   qs = q'((lane&15)*4 + (lane>>4))  — the exact lane->address map that
// measured ZERO bank conflicts in the 16x16 kernel (R2). Staging source is
// the inverse map (global pre-permute, linear LDS dest).
// ---------------------------------------------------------------------------

__device__ __forceinline__ void gload16(const __hip_bfloat16* g, char* l) {
    __builtin_amdgcn_global_load_lds((const __attribute__((address_space(1))) void*)g,
                                     (__attribute__((address_space(3))) void*)l,
                                     16, 0, 0);
}

#define STAGE(base, kb, bufi, slot) do {                                          \
    gload16((base) + (kb) + gOff0, smemc + (bufi)*32768 + (slot)*16384 + lOff0);  \
    gload16((base) + (kb) + gOff1, smemc + (bufi)*32768 + (slot)*16384 + lOff1);  \
} while (0)

// 6 x ds_read_b128: A frags (4 x 32 rows) + B frags (2 x 32 cols), one kstep.
#define LOADK(ks, bufc)                                                       \
    a0 = *(const bf16x8*)(smemc + (bufc)*32768 + offA[0][ks]);                \
    a1 = *(const bf16x8*)(smemc + (bufc)*32768 + offA[1][ks]);                \
    a2 = *(const bf16x8*)(smemc + (bufc)*32768 + offA[2][ks]);                \
    a3 = *(const bf16x8*)(smemc + (bufc)*32768 + offA[3][ks]);                \
    b0 = *(const bf16x8*)(smemc + (bufc)*32768 + 16384 + offB[0][ks]);        \
    b1 = *(const bf16x8*)(smemc + (bufc)*32768 + 16384 + offB[1][ks]);

#define MFMA8 do {                                                                  \
    acc[0][0] = __builtin_amdgcn_mfma_f32_32x32x16_bf16(a0, b0, acc[0][0], 0,0,0);  \
    acc[1][0] = __builtin_amdgcn_mfma_f32_32x32x16_bf16(a1, b0, acc[1][0], 0,0,0);  \
    acc[2][0] = __builtin_amdgcn_mfma_f32_32x32x16_bf16(a2, b0, acc[2][0], 0,0,0);  \
    acc[3][0] = __builtin_amdgcn_mfma_f32_32x32x16_bf16(a3, b0, acc[3][0], 0,0,0);  \
    acc[0][1] = __builtin_amdgcn_mfma_f32_32x32x16_bf16(a0, b1, acc[0][1], 0,0,0);  \
    acc[1][1] = __builtin_amdgcn_mfma_f32_32x32x16_bf16(a1, b1, acc[1][1], 0,0,0);  \
    acc[2][1] = __builtin_amdgcn_mfma_f32_32x32x16_bf16(a2, b1, acc[2][1], 0,0,0);  \
    acc[3][1] = __builtin_amdgcn_mfma_f32_32x32x16_bf16(a3, b1, acc[3][1], 0,0,0);  \
} while (0)

#define BARRIER_IN do {                                     \
    __builtin_amdgcn_sched_barrier(0);                      \
    __builtin_amdgcn_s_barrier();                           \
    asm volatile("s_waitcnt lgkmcnt(0)" ::: "memory");      \
    __builtin_amdgcn_sched_barrier(0);                      \
    __builtin_amdgcn_s_setprio(1);                          \
} while (0)

#define BARRIER_OUT do {                                    \
    __builtin_amdgcn_s_setprio(0);                          \
    __builtin_amdgcn_sched_barrier(0);                      \
    __builtin_amdgcn_s_barrier();                           \
    __builtin_amdgcn_sched_barrier(0);                      \
} while (0)

#define WAIT4 asm volatile("s_waitcnt vmcnt(4)" ::: "memory")
#define WAIT0 asm volatile("s_waitcnt vmcnt(0)" ::: "memory")
#define WNONE do {} while (0)

// One K-tile, one barrier-pair. bufc = t%3 (compile-time), bufs = (t+2)%3.
#define KTILE3(t, bufc, bufs, SG, WT) do {                          \
    LOADK(0, bufc);                                                 \
    if (SG) { STAGE(Abase, ((t)+2)*32, bufs, 0);                    \
              STAGE(Bbase, ((t)+2)*32, bufs, 1); }                  \
    BARRIER_IN;                                                     \
    MFMA8;                                                          \
    LOADK(1, bufc);                                                 \
    asm volatile("s_waitcnt lgkmcnt(0)" ::: "memory");              \
    __builtin_amdgcn_sched_barrier(0);                              \
    MFMA8;                                                          \
    WT;                                                             \
    BARRIER_OUT;                                                    \
} while (0)

__global__ __launch_bounds__(512, 2) void gemm3_kernel(const __hip_bfloat16* __restrict__ A,
                                                       const __hip_bfloat16* __restrict__ Wb,
                                                       const float* __restrict__ bias,
                                                       float* __restrict__ C) {
    __shared__ __align__(16) __hip_bfloat16 smem[3][2][8192];  // 96 KiB
    char* smemc = (char*)&smem[0][0][0];

    const int tid  = threadIdx.x;
    const int lane = tid & 63;
    const int wid  = tid >> 6;        // 0..7
    const int wr   = wid >> 2;        // 0..1  (M half)
    const int wc   = wid & 3;         // 0..3  (N quarter)

    // T1: XCD-aware swizzle (nwg=512, 512%8==0 -> bijective).
    const int bid = blockIdx.x;
    const int swz = (bid & 7) * 64 + (bid >> 3);
    const int bn  = swz >> 6;         // 0..7
    const int bm  = swz & 63;         // 0..63

    const __hip_bfloat16* Abase = A  + (size_t)bm * 256 * KDIM;
    const __hip_bfloat16* Bbase = Wb + (size_t)bn * 256 * KDIM;

    // --- staging: inverse of the storage bijection (global pre-permute) ---
    // chunk c -> (row r, slot s):  ks=(c>>6)&1, q'=c&63, q=q'^((q'>>3)&7),
    // vslot=q&3, r=(c>>7)*32+(vslot&1)*16+(q>>2), s=ks*2+(vslot>>1).
    int gOff0, gOff1;
    {
        const int c0 = wid * 64 + lane;
        const int c1 = 512 + c0;
        int ks, qp, q, vs, r, s;
        ks = (c0 >> 6) & 1; qp = c0 & 63; q = qp ^ ((qp >> 3) & 7); vs = q & 3;
        r  = (c0 >> 7) * 32 + (vs & 1) * 16 + (q >> 2); s = ks * 2 + (vs >> 1);
        gOff0 = r * KDIM + s * 8;
        ks = (c1 >> 6) & 1; qp = c1 & 63; q = qp ^ ((qp >> 3) & 7); vs = q & 3;
        r  = (c1 >> 7) * 32 + (vs & 1) * 16 + (q >> 2); s = ks * 2 + (vs >> 1);
        gOff1 = r * KDIM + s * 8;
    }
    const int lOff0 = wid * 1024;          // bytes (wave-uniform, linear dest)
    const int lOff1 = 8192 + wid * 1024;

    // --- fragment read offsets: base + ks*1024 + qs*16 (R2's proven map) ---
    const int qv   = (lane & 15) * 4 + (lane >> 4);
    const int qs16 = (qv ^ ((qv >> 3) & 7)) * 16;
    int offA[4][2], offB[2][2];
#pragma unroll
    for (int mf = 0; mf < 4; ++mf)
#pragma unroll
        for (int ks = 0; ks < 2; ++ks)
            offA[mf][ks] = (wr * 4 + mf) * 2048 + ks * 1024 + qs16;
#pragma unroll
    for (int nf = 0; nf < 2; ++nf)
#pragma unroll
        for (int ks = 0; ks < 2; ++ks)
            offB[nf][ks] = (wc * 2 + nf) * 2048 + ks * 1024 + qs16;

    f32x16 acc[4][2];
#pragma unroll
    for (int mf = 0; mf < 4; ++mf)
#pragma unroll
        for (int nf = 0; nf < 2; ++nf)
#pragma unroll
            for (int r = 0; r < 16; ++r)
                acc[mf][nf][r] = 0.f;

    bf16x8 a0, a1, a2, a3, b0, b1;

    // --- prologue: stage tile0 -> buf0, tile1 -> buf1 (8 loads/wave) ---
    STAGE(Abase,  0, 0, 0);
    STAGE(Bbase,  0, 0, 1);
    STAGE(Abase, 32, 1, 0);
    STAGE(Bbase, 32, 1, 1);
    WAIT4;                    // tile0 landed; tile1's 4 may stay in flight
    __builtin_amdgcn_sched_barrier(0);
    __builtin_amdgcn_s_barrier();
    __builtin_amdgcn_sched_barrier(0);

    // --- main loop: KDIM/32 = 64 K-tiles, buf = t%3 ---
    for (int t = 0; t < 60; t += 3) {
        KTILE3(t,     0, 2, 1, WAIT4);
        KTILE3(t + 1, 1, 0, 1, WAIT4);
        KTILE3(t + 2, 2, 1, 1, WAIT4);
    }
    KTILE3(60, 0, 2, 1, WAIT4);   // stages t62
    KTILE3(61, 1, 0, 1, WAIT4);   // stages t63
    KTILE3(62, 2, 1, 0, WAIT0);   // drain: t63 landed
    KTILE3(63, 0, 1, 0, WNONE);

    // --- epilogue: 32x32 C/D layout col=lane&31, row=(reg&3)+8*(reg>>2)+4*(lane>>5) ---
    const int l31    = lane & 31;
    const int rupper = 4 * (lane >> 5);
#pragma unroll
    for (int nf = 0; nf < 2; ++nf) {
        const int cg = bn * 256 + wc * 64 + nf * 32 + l31;
        const float bv = bias[cg];
#pragma unroll
        for (int mf = 0; mf < 4; ++mf) {
            const size_t rb = (size_t)bm * 256 + wr * 128 + mf * 32 + rupper;
#pragma unroll
            for (int reg = 0; reg < 16; ++reg) {
                const int row = (reg & 3) + 8 * (reg >> 2);
                C[(rb + row) * NDIM + cg] = acc[mf][nf][reg] + bv;
            }
        }
    }
}

// ---------------------------------------------------------------------------
// Fallback: naive fused fp32 GEMM (only if workspace too small).
// ---------------------------------------------------------------------------
__global__ void naive_kernel(const float* __restrict__ x,
                             const float* __restrict__ leaf,
                             const float* __restrict__ W,
                             const float* __restrict__ bias,
                             float* __restrict__ out) {
    long idx = (long)blockIdx.x * blockDim.x + threadIdx.x;
    if (idx >= (long)MROWS * NDIM) return;
    int  o = (int)(idx % NDIM);
    long m = idx / NDIM;
    int o2 = o / 169, o1 = (o / 13) % 13, o0 = o % 13;
    float acc = 0.f;
    for (int i = 0; i < KDIM; ++i) {
        int i2 = i / 169, i1 = (i / 13) % 13, i0 = i % 13;
        float d = 0.f;
#pragma unroll
        for (int r = 0; r < RANKD; ++r)
            d += leaf[( r     * LEAFD + o2) * LEAFD + i2]
               * leaf[((4 + r) * LEAFD + o1) * LEAFD + i1]
               * leaf[((8 + r) * LEAFD + o0) * LEAFD + i0];
        acc += x[m * KDIM + i] * (W[(long)o * KDIM + i] + d);
    }
    out[idx] = acc + bias[o];
}

// ---------------------------------------------------------------------------
extern "C" void kernel_launch(void* const* d_in, const int* in_sizes, int n_in,
                              void* d_out, int out_size, void* d_ws, size_t ws_size,
                              hipStream_t stream) {
    const float* x      = (const float*)d_in[0];
    const float* leaf   = (const float*)d_in[1];
    const float* weight = (const float*)d_in[2];
    const float* bias   = (const float*)d_in[3];
    float* out = (float*)d_out;

    const size_t needA = (size_t)MROWS * KDIM * sizeof(__hip_bfloat16);  // 64 MiB
    const size_t needW = (size_t)NDIM  * KDIM * sizeof(__hip_bfloat16);  // 8 MiB

    if (ws_size >= needA + needW) {
        __hip_bfloat16* xb = (__hip_bfloat16*)d_ws;
        __hip_bfloat16* wb = (__hip_bfloat16*)((char*)d_ws + needA);
        build_w_kernel<<<(NDIM * KDIM + 255) / 256, 256, 0, stream>>>(weight, leaf, wb);
        cvt_kernel<<<2048, 256, 0, stream>>>(x, xb, MROWS * KDIM);
        gemm3_kernel<<<(MROWS / 256) * (NDIM / 256), 512, 0, stream>>>(xb, wb, bias, out);
    } else {
        long total = (long)MROWS * NDIM;
        naive_kernel<<<(int)((total + 255) / 256), 256, 0, stream>>>(x, leaf, weight, bias, out);
    }
}

// Round 7
// 211.216 us; speedup vs baseline: 1.0260x; 1.0260x over previous
//
#include <hip/hip_runtime.h>
#include <hip/hip_bf16.h>
#include <stdint.h>

#define MROWS 16384   // B*S
#define KDIM  2048
#define NDIM  2048
#define LEAFD 13
#define RANKD 4

typedef __bf16 bf16x8 __attribute__((ext_vector_type(8)));
typedef float  f32x16 __attribute__((ext_vector_type(16)));

// ---------------------------------------------------------------------------
// Kernel 1: w_bf[o,i] = bf16( weight[o,i] + sum_r L0[r,o2,i2]*L1[r,o1,i1]*L2[r,o0,i0] )
// ---------------------------------------------------------------------------
__global__ void build_w_kernel(const float* __restrict__ weight,
                               const float* __restrict__ leaf,
                               __hip_bfloat16* __restrict__ wbf) {
    __shared__ float ll[3 * RANKD * LEAFD * LEAFD];
    for (int t = threadIdx.x; t < 3 * RANKD * LEAFD * LEAFD; t += blockDim.x)
        ll[t] = leaf[t];
    __syncthreads();
    int idx = blockIdx.x * blockDim.x + threadIdx.x;
    if (idx >= NDIM * KDIM) return;
    int o = idx / KDIM, i = idx % KDIM;
    int o2 = o / 169, o1 = (o / 13) % 13, o0 = o % 13;
    int i2 = i / 169, i1 = (i / 13) % 13, i0 = i % 13;
    float d = 0.f;
#pragma unroll
    for (int r = 0; r < RANKD; ++r) {
        float a = ll[( r            * LEAFD + o2) * LEAFD + i2];
        float b = ll[((RANKD   + r) * LEAFD + o1) * LEAFD + i1];
        float c = ll[((2*RANKD + r) * LEAFD + o0) * LEAFD + i0];
        d += a * b * c;
    }
    wbf[idx] = __float2bfloat16(weight[idx] + d);
}

// ---------------------------------------------------------------------------
// Kernel 2: fp32 -> bf16 conversion of activations (8 floats/thread)
// ---------------------------------------------------------------------------
__global__ void cvt_kernel(const float* __restrict__ x,
                           __hip_bfloat16* __restrict__ xb, int n) {
    long stride = (long)gridDim.x * blockDim.x * 8;
    for (long idx = ((long)blockIdx.x * blockDim.x + threadIdx.x) * 8; idx < n; idx += stride) {
        float4 v0 = *reinterpret_cast<const float4*>(x + idx);
        float4 v1 = *reinterpret_cast<const float4*>(x + idx + 4);
        __hip_bfloat16 tmp[8];
        tmp[0] = __float2bfloat16(v0.x); tmp[1] = __float2bfloat16(v0.y);
        tmp[2] = __float2bfloat16(v0.z); tmp[3] = __float2bfloat16(v0.w);
        tmp[4] = __float2bfloat16(v1.x); tmp[5] = __float2bfloat16(v1.y);
        tmp[6] = __float2bfloat16(v1.z); tmp[7] = __float2bfloat16(v1.w);
        *reinterpret_cast<uint4*>(xb + idx) = *reinterpret_cast<const uint4*>(tmp);
    }
}

// ---------------------------------------------------------------------------
// Kernel 3: 256x256 tile, BK=32, 32x32x16 MFMA, 4-buffer LDS (128 KB),
// cross-barrier k0-fragment register prefetch (parity E/O), zero-conflict
// coalescing-preserving swizzle.
//
// LDS storage: 16B-chunk (row r, slot s in 0..3) of a 256x32 slab stored at
// 16B-position r*4 + (s ^ ((r>>1)&3)).
//   * fragment reads: 64 lanes hit all 8 bank-spans exactly 8x -> 0 conflicts
//   * staging: wave loads 16 contiguous rows, 4 lanes cover each 64B row
//     (permuted within the row) -> coalesces to one 64B transaction per row
//
// Per tile t (buf c=t%4, parity p=t&1):
//   STAGE(t+3 -> buf (t+3)%4)                        [4 gload_lds]
//   MFMA8(k0, regs[p])          (loaded during t-1 -> no lgkm stall)
//   read k1(t) from buf c; read k0(t+1) from buf (t+1)%4 -> regs[!p]
//   MFMA8(k1)                   (compiler waits only the k1 reads)
//   vmcnt(4)  [forces S(t+2) landed - source of t+1's k0-prefetch]
//   s_barrier
// ---------------------------------------------------------------------------

__device__ __forceinline__ void gload16(const __hip_bfloat16* g, char* l) {
    __builtin_amdgcn_global_load_lds((const __attribute__((address_space(1))) void*)g,
                                     (__attribute__((address_space(3))) void*)l,
                                     16, 0, 0);
}

#define SB __builtin_amdgcn_sched_barrier(0)
#define WAIT4 asm volatile("s_waitcnt vmcnt(4)" ::: "memory")
#define WAIT0 asm volatile("s_waitcnt vmcnt(0)" ::: "memory")
#define WNONE do {} while (0)

#define STAGEPAIR(KB, BS) do {                                                  \
    gload16(Abase + (KB) + gOff0, smemc + (BS)*32768 + lOff0);                  \
    gload16(Abase + (KB) + gOff1, smemc + (BS)*32768 + lOff1);                  \
    gload16(Bbase + (KB) + gOff0, smemc + (BS)*32768 + 16384 + lOff0);          \
    gload16(Bbase + (KB) + gOff1, smemc + (BS)*32768 + 16384 + lOff1);          \
} while (0)

#define RD(off) (*(const bf16x8*)(smemc + (off)))

#define MFMA8R(A0,A1,A2,A3,B0,B1) do {                                              \
    acc00 = __builtin_amdgcn_mfma_f32_32x32x16_bf16(A0, B0, acc00, 0,0,0);          \
    acc10 = __builtin_amdgcn_mfma_f32_32x32x16_bf16(A1, B0, acc10, 0,0,0);          \
    acc20 = __builtin_amdgcn_mfma_f32_32x32x16_bf16(A2, B0, acc20, 0,0,0);          \
    acc30 = __builtin_amdgcn_mfma_f32_32x32x16_bf16(A3, B0, acc30, 0,0,0);          \
    acc01 = __builtin_amdgcn_mfma_f32_32x32x16_bf16(A0, B1, acc01, 0,0,0);          \
    acc11 = __builtin_amdgcn_mfma_f32_32x32x16_bf16(A1, B1, acc11, 0,0,0);          \
    acc21 = __builtin_amdgcn_mfma_f32_32x32x16_bf16(A2, B1, acc21, 0,0,0);          \
    acc31 = __builtin_amdgcn_mfma_f32_32x32x16_bf16(A3, B1, acc31, 0,0,0);          \
} while (0)

// BC: current buf (0..3), BN: next buf, BS: stage-dest buf, KB: stage k-elems
// A0..B1: current-tile k0 regs; N0..M1: next-tile k0 regs (other parity)
#define TILE(BC, BN, BS, KB, SG, WT, A0,A1,A2,A3,B0,B1, N0,N1,N2,N3,M0,M1) do { \
    if (SG) STAGEPAIR(KB, BS);                                                  \
    SB;                                                                         \
    __builtin_amdgcn_s_setprio(1);                                              \
    MFMA8R(A0,A1,A2,A3,B0,B1);                                                  \
    __builtin_amdgcn_s_setprio(0);                                              \
    SB;                                                                         \
    c0 = RD((BC)*32768 + aB + 0*2048 + lk1);                                    \
    c1 = RD((BC)*32768 + aB + 1*2048 + lk1);                                    \
    c2 = RD((BC)*32768 + aB + 2*2048 + lk1);                                    \
    c3 = RD((BC)*32768 + aB + 3*2048 + lk1);                                    \
    d0 = RD((BC)*32768 + bB + 0*2048 + lk1);                                    \
    d1 = RD((BC)*32768 + bB + 1*2048 + lk1);                                    \
    N0 = RD((BN)*32768 + aB + 0*2048 + lk0);                                    \
    N1 = RD((BN)*32768 + aB + 1*2048 + lk0);                                    \
    N2 = RD((BN)*32768 + aB + 2*2048 + lk0);                                    \
    N3 = RD((BN)*32768 + aB + 3*2048 + lk0);                                    \
    M0 = RD((BN)*32768 + bB + 0*2048 + lk0);                                    \
    M1 = RD((BN)*32768 + bB + 1*2048 + lk0);                                    \
    SB;                                                                         \
    __builtin_amdgcn_s_setprio(1);                                              \
    MFMA8R(c0,c1,c2,c3,d0,d1);                                                  \
    __builtin_amdgcn_s_setprio(0);                                              \
    WT;                                                                         \
    SB;                                                                         \
    __builtin_amdgcn_s_barrier();                                               \
    SB;                                                                         \
} while (0)

#define TILE_LAST(BC, A0,A1,A2,A3,B0,B1) do {                                   \
    __builtin_amdgcn_s_setprio(1);                                              \
    MFMA8R(A0,A1,A2,A3,B0,B1);                                                  \
    __builtin_amdgcn_s_setprio(0);                                              \
    c0 = RD((BC)*32768 + aB + 0*2048 + lk1);                                    \
    c1 = RD((BC)*32768 + aB + 1*2048 + lk1);                                    \
    c2 = RD((BC)*32768 + aB + 2*2048 + lk1);                                    \
    c3 = RD((BC)*32768 + aB + 3*2048 + lk1);                                    \
    d0 = RD((BC)*32768 + bB + 0*2048 + lk1);                                    \
    d1 = RD((BC)*32768 + bB + 1*2048 + lk1);                                    \
    __builtin_amdgcn_s_setprio(1);                                              \
    MFMA8R(c0,c1,c2,c3,d0,d1);                                                  \
    __builtin_amdgcn_s_setprio(0);                                              \
} while (0)

__global__ __launch_bounds__(512, 2) void gemm4_kernel(const __hip_bfloat16* __restrict__ A,
                                                       const __hip_bfloat16* __restrict__ Wb,
                                                       const float* __restrict__ bias,
                                                       float* __restrict__ C) {
    __shared__ __align__(16) __hip_bfloat16 smem[4][2][8192];  // 128 KiB
    char* smemc = (char*)smem;

    const int tid  = threadIdx.x;
    const int lane = tid & 63;
    const int wid  = tid >> 6;        // 0..7
    const int wr   = wid >> 2;        // 0..1  (M half)
    const int wc   = wid & 3;         // 0..3  (N quarter)

    // T1: XCD-aware swizzle (nwg=512, 512%8==0 -> bijective).
    const int bid = blockIdx.x;
    const int swz = (bid & 7) * 64 + (bid >> 3);
    const int bn  = swz >> 6;         // 0..7
    const int bm  = swz & 63;         // 0..63

    const __hip_bfloat16* Abase = A  + (size_t)bm * 256 * KDIM;
    const __hip_bfloat16* Bbase = Wb + (size_t)bn * 256 * KDIM;

    // --- staging source (inverse of the storage map; linear LDS dest) ---
    // position p holds chunk (r = p>>2, slot = (p&3) ^ ((p>>3)&3))
    const int r16   = wid * 16 + (lane >> 2);
    const int slt   = (lane & 3) ^ ((lane >> 3) & 3);
    const int gOff0 = r16 * KDIM + slt * 8;          // elements
    const int gOff1 = gOff0 + 128 * KDIM;
    const int lOff0 = wid * 1024;                    // bytes (wave-uniform)
    const int lOff1 = 8192 + wid * 1024;

    // --- fragment read lane offsets (within a 16 KB slab) ---
    const int l31 = lane & 31;
    const int h   = lane >> 5;
    const int lk0 = l31 * 64 + (((0 * 2 + h) ^ ((l31 >> 1) & 3)) << 4);
    const int lk1 = l31 * 64 + (((1 * 2 + h) ^ ((l31 >> 1) & 3)) << 4);
    const int aB  = wr * 8192;            // A region base within buf
    const int bB  = 16384 + wc * 4096;    // B region base within buf

    f32x16 acc00{}, acc10{}, acc20{}, acc30{}, acc01{}, acc11{}, acc21{}, acc31{};

    bf16x8 aE0, aE1, aE2, aE3, bE0, bE1;   // k0 regs, even tiles
    bf16x8 aO0, aO1, aO2, aO3, bO0, bO1;   // k0 regs, odd tiles
    bf16x8 c0, c1, c2, c3, d0, d1;         // k1 regs (single-buffered)

    // --- prologue: stage tiles 0,1,2 -> bufs 0,1,2 (12 gloads/thread) ---
    STAGEPAIR( 0, 0);
    STAGEPAIR(32, 1);
    STAGEPAIR(64, 2);
    asm volatile("s_waitcnt vmcnt(8)" ::: "memory");   // S0 landed
    SB; __builtin_amdgcn_s_barrier(); SB;
    aE0 = RD(aB + 0*2048 + lk0);
    aE1 = RD(aB + 1*2048 + lk0);
    aE2 = RD(aB + 2*2048 + lk0);
    aE3 = RD(aB + 3*2048 + lk0);
    bE0 = RD(bB + 0*2048 + lk0);
    bE1 = RD(bB + 1*2048 + lk0);
    asm volatile("s_waitcnt vmcnt(4)" ::: "memory");   // S1 landed
    SB; __builtin_amdgcn_s_barrier(); SB;

    // --- main loop: tiles 0..55, then tail 56..63 ---
    for (int t = 0; t < 56; t += 4) {
        TILE(0, 1, 3, (t+3)*32, 1, WAIT4, aE0,aE1,aE2,aE3,bE0,bE1, aO0,aO1,aO2,aO3,bO0,bO1);
        TILE(1, 2, 0, (t+4)*32, 1, WAIT4, aO0,aO1,aO2,aO3,bO0,bO1, aE0,aE1,aE2,aE3,bE0,bE1);
        TILE(2, 3, 1, (t+5)*32, 1, WAIT4, aE0,aE1,aE2,aE3,bE0,bE1, aO0,aO1,aO2,aO3,bO0,bO1);
        TILE(3, 0, 2, (t+6)*32, 1, WAIT4, aO0,aO1,aO2,aO3,bO0,bO1, aE0,aE1,aE2,aE3,bE0,bE1);
    }
    TILE(0, 1, 3, 59*32, 1, WAIT4, aE0,aE1,aE2,aE3,bE0,bE1, aO0,aO1,aO2,aO3,bO0,bO1); // t=56
    TILE(1, 2, 0, 60*32, 1, WAIT4, aO0,aO1,aO2,aO3,bO0,bO1, aE0,aE1,aE2,aE3,bE0,bE1); // t=57
    TILE(2, 3, 1, 61*32, 1, WAIT4, aE0,aE1,aE2,aE3,bE0,bE1, aO0,aO1,aO2,aO3,bO0,bO1); // t=58
    TILE(3, 0, 2, 62*32, 1, WAIT4, aO0,aO1,aO2,aO3,bO0,bO1, aE0,aE1,aE2,aE3,bE0,bE1); // t=59
    TILE(0, 1, 3, 63*32, 1, WAIT4, aE0,aE1,aE2,aE3,bE0,bE1, aO0,aO1,aO2,aO3,bO0,bO1); // t=60
    TILE(1, 2, 0, 0,     0, WAIT0, aO0,aO1,aO2,aO3,bO0,bO1, aE0,aE1,aE2,aE3,bE0,bE1); // t=61
    TILE(2, 3, 1, 0,     0, WNONE, aE0,aE1,aE2,aE3,bE0,bE1, aO0,aO1,aO2,aO3,bO0,bO1); // t=62
    TILE_LAST(3, aO0,aO1,aO2,aO3,bO0,bO1);                                             // t=63

    // --- epilogue: 32x32 C/D layout col=lane&31, row=(reg&3)+8*(reg>>2)+4*(lane>>5) ---
    const int rupper = 4 * h;
    f32x16* accp[4][2] = {{&acc00,&acc01},{&acc10,&acc11},{&acc20,&acc21},{&acc30,&acc31}};
#pragma unroll
    for (int nf = 0; nf < 2; ++nf) {
        const int cg = bn * 256 + wc * 64 + nf * 32 + l31;
        const float bv = bias[cg];
#pragma unroll
        for (int mf = 0; mf < 4; ++mf) {
            const size_t rb = (size_t)bm * 256 + wr * 128 + mf * 32 + rupper;
            const f32x16 av = *accp[mf][nf];
#pragma unroll
            for (int reg = 0; reg < 16; ++reg) {
                const int row = (reg & 3) + 8 * (reg >> 2);
                C[(rb + row) * NDIM + cg] = av[reg] + bv;
            }
        }
    }
}

// ---------------------------------------------------------------------------
// Fallback: naive fused fp32 GEMM (only if workspace too small).
// ---------------------------------------------------------------------------
__global__ void naive_kernel(const float* __restrict__ x,
                             const float* __restrict__ leaf,
                             const float* __restrict__ W,
                             const float* __restrict__ bias,
                             float* __restrict__ out) {
    long idx = (long)blockIdx.x * blockDim.x + threadIdx.x;
    if (idx >= (long)MROWS * NDIM) return;
    int  o = (int)(idx % NDIM);
    long m = idx / NDIM;
    int o2 = o / 169, o1 = (o / 13) % 13, o0 = o % 13;
    float acc = 0.f;
    for (int i = 0; i < KDIM; ++i) {
        int i2 = i / 169, i1 = (i / 13) % 13, i0 = i % 13;
        float d = 0.f;
#pragma unroll
        for (int r = 0; r < RANKD; ++r)
            d += leaf[( r     * LEAFD + o2) * LEAFD + i2]
               * leaf[((4 + r) * LEAFD + o1) * LEAFD + i1]
               * leaf[((8 + r) * LEAFD + o0) * LEAFD + i0];
        acc += x[m * KDIM + i] * (W[(long)o * KDIM + i] + d);
    }
    out[idx] = acc + bias[o];
}

// ---------------------------------------------------------------------------
extern "C" void kernel_launch(void* const* d_in, const int* in_sizes, int n_in,
                              void* d_out, int out_size, void* d_ws, size_t ws_size,
                              hipStream_t stream) {
    const float* x      = (const float*)d_in[0];
    const float* leaf   = (const float*)d_in[1];
    const float* weight = (const float*)d_in[2];
    const float* bias   = (const float*)d_in[3];
    float* out = (float*)d_out;

    const size_t needA = (size_t)MROWS * KDIM * sizeof(__hip_bfloat16);  // 64 MiB
    const size_t needW = (size_t)NDIM  * KDIM * sizeof(__hip_bfloat16);  // 8 MiB

    if (ws_size >= needA + needW) {
        __hip_bfloat16* xb = (__hip_bfloat16*)d_ws;
        __hip_bfloat16* wb = (__hip_bfloat16*)((char*)d_ws + needA);
        build_w_kernel<<<(NDIM * KDIM + 255) / 256, 256, 0, stream>>>(weight, leaf, wb);
        cvt_kernel<<<2048, 256, 0, stream>>>(x, xb, MROWS * KDIM);
        gemm4_kernel<<<(MROWS / 256) * (NDIM / 256), 512, 0, stream>>>(xb, wb, bias, out);
    } else {
        long total = (long)MROWS * NDIM;
        naive_kernel<<<(int)((total + 255) / 256), 256, 0, stream>>>(x, leaf, weight, bias, out);
    }
}